// Round 1
// baseline (1751.632 us; speedup 1.0000x reference)
//
#include <hip/hip_runtime.h>
#include <math.h>

// Problem dims (fixed by reference)
//   B=128, S=64, H=128, STATIC=DYNAMIC=2
// Outputs: tour_idx [B,S] (written as float), tour_logp [B,S]  -> d_out 16384 f32

// ---------------- ws layout (float offsets) ----------------
#define WS_WHH_T 0                       // [128][384]  whh_T[k][j] = whh[j][k]
#define WS_W3T   49152                   // [128][128]  W3T[k][h] = attn_W[h][256+k]
#define WS_M     65536                   // [384][2]    M = wih @ decoder_w
#define WS_C     66304                   // [384]       c = wih @ decoder_b + bih
#define WS_PREA  66688                   // [B][128][64] W1@static_h + W2@dynamic_h
#define WS_PREP  (WS_PREA + 128*8192)    // [B][128][64] P1@static_h
#define WS_Q     (WS_PREP + 128*8192)    // [B][128][64] P2@static_h

// ---------------- tiny precompute: transposes + GRU input-path folding ----
__global__ __launch_bounds__(256) void prep_small(
    const float* __restrict__ whh, const float* __restrict__ attn_W,
    const float* __restrict__ wih, const float* __restrict__ decw,
    const float* __restrict__ decb, const float* __restrict__ bih,
    float* __restrict__ ws) {
  int gid = blockIdx.x * 256 + threadIdx.x;
  int nth = gridDim.x * 256;
  float* whhT = ws + WS_WHH_T;
  float* W3T  = ws + WS_W3T;
  float* Mm   = ws + WS_M;
  float* Cc   = ws + WS_C;
  for (int idx = gid; idx < 384 * 128; idx += nth) {
    int k = idx / 384, j = idx % 384;        // out coalesced over j
    whhT[idx] = whh[j * 128 + k];
  }
  for (int idx = gid; idx < 128 * 128; idx += nth) {
    int k = idx / 128, h = idx % 128;
    W3T[idx] = attn_W[h * 384 + 256 + k];
  }
  if (gid < 384) {
    int j = gid;
    float m0 = 0.f, m1 = 0.f, cc = 0.f;
    for (int k = 0; k < 128; ++k) {
      float w = wih[j * 128 + k];
      m0 += w * decw[k * 2 + 0];
      m1 += w * decw[k * 2 + 1];
      cc += w * decb[k];
    }
    Mm[j * 2 + 0] = m0;
    Mm[j * 2 + 1] = m1;
    Cc[j] = cc + bih[j];
  }
}

// ---------------- big precompute: preA / preP / Q per batch --------------
// grid: 1024 blocks = (b, hq): b = bid>>3, hq = bid&7 owns 16 h-rows
__global__ __launch_bounds__(256) void prep_big(
    const float* __restrict__ statics, const float* __restrict__ dynamics,
    const float* __restrict__ sw, const float* __restrict__ sb,
    const float* __restrict__ dw, const float* __restrict__ db,
    const float* __restrict__ attn_W, const float* __restrict__ ptr_W,
    float* __restrict__ ws) {
  __shared__ __align__(16) float sh[128 * 64];
  __shared__ __align__(16) float dh[128 * 64];
  __shared__ float st[128];
  __shared__ float dy[128];
  int b = blockIdx.x >> 3;
  int hq = blockIdx.x & 7;
  int t = threadIdx.x;
  if (t < 128) st[t] = statics[b * 128 + t];
  else         dy[t - 128] = dynamics[b * 128 + (t - 128)];
  __syncthreads();
  for (int e = t; e < 8192; e += 256) {
    int h = e >> 6, s = e & 63;
    sh[e] = sw[h * 2 + 0] * st[s] + sw[h * 2 + 1] * st[64 + s] + sb[h];
    dh[e] = dw[h * 2 + 0] * dy[s] + dw[h * 2 + 1] * dy[64 + s] + db[h];
  }
  __syncthreads();
  int hh = hq * 16 + (t >> 4);
  int s0 = (t & 15) * 4;
  float4 pA = {0, 0, 0, 0}, pP = {0, 0, 0, 0}, qq = {0, 0, 0, 0};
  for (int k = 0; k < 128; ++k) {
    float4 sv = *(const float4*)&sh[k * 64 + s0];
    float4 dv = *(const float4*)&dh[k * 64 + s0];
    float w1 = attn_W[hh * 384 + k];
    float w2 = attn_W[hh * 384 + 128 + k];
    float p1 = ptr_W[hh * 256 + k];
    float p2 = ptr_W[hh * 256 + 128 + k];
    pA.x += w1 * sv.x + w2 * dv.x;  pA.y += w1 * sv.y + w2 * dv.y;
    pA.z += w1 * sv.z + w2 * dv.z;  pA.w += w1 * sv.w + w2 * dv.w;
    pP.x += p1 * sv.x;  pP.y += p1 * sv.y;  pP.z += p1 * sv.z;  pP.w += p1 * sv.w;
    qq.x += p2 * sv.x;  qq.y += p2 * sv.y;  qq.z += p2 * sv.z;  qq.w += p2 * sv.w;
  }
  int o = b * 8192 + hh * 64 + s0;
  *(float4*)&ws[WS_PREA + o] = pA;
  *(float4*)&ws[WS_PREP + o] = pP;
  *(float4*)&ws[WS_Q + o]    = qq;
}

// ---------------- main recurrence: 1 block per batch, 64 steps ----------
__global__ __launch_bounds__(256) void drl4tsp_main(
    const float* __restrict__ statics, const float* __restrict__ x0,
    const float* __restrict__ bhh_g, const float* __restrict__ attn_v,
    const float* __restrict__ ptr_v, const float* __restrict__ ws,
    float* __restrict__ out) {
  // padded (65) tiles to kill LDS bank conflicts on column reads
  __shared__ __align__(16) float preA[128 * 65];
  __shared__ __align__(16) float preP[128 * 65];
  __shared__ __align__(16) float Qs[128 * 65];
  __shared__ float stt[128];      // raw static[b] for dec_in gather
  __shared__ float h_lds[128];
  __shared__ float z_lds[128];
  __shared__ float u3[128];
  __shared__ float u2[128];
  __shared__ float part[256];
  __shared__ __align__(16) float red[256];
  __shared__ float attns[64];
  __shared__ float dec[2];

  int b = blockIdx.x;
  int t = threadIdx.x;
  const float* pA_g = ws + WS_PREA + b * 8192;
  const float* pP_g = ws + WS_PREP + b * 8192;
  const float* q_g  = ws + WS_Q + b * 8192;
  for (int e = t; e < 8192; e += 256) {
    int h = e >> 6, s = e & 63;
    preA[h * 65 + s] = pA_g[e];
    preP[h * 65 + s] = pP_g[e];
    Qs[h * 65 + s]   = q_g[e];
  }
  if (t < 128) { stt[t] = statics[b * 128 + t]; h_lds[t] = 0.f; }
  if (t < 2) dec[t] = x0[t];
  __syncthreads();

  const float* whhT = ws + WS_WHH_T;
  const float* W3T  = ws + WS_W3T;
  const float* Mm   = ws + WS_M;
  const float* Cc   = ws + WS_C;

  const int j = t;            // rows: t<128 -> r-gate, 128..255 -> z-gate
  const int j2 = t + 256;     // t<128 also owns n-gate row
  const bool lo = (t < 128);

  for (int step = 0; step < 64; ++step) {
    // ---- GRU gates: gi folded to M@dec + c;  gh = whh@h + bhh ----
    float d0 = dec[0], d1 = dec[1];
    float gi1 = Mm[j * 2 + 0] * d0 + Mm[j * 2 + 1] * d1 + Cc[j];
    float gh1 = bhh_g[j];
    float gi2 = 0.f, gh2 = 0.f;
    if (lo) {
      gi2 = Mm[j2 * 2 + 0] * d0 + Mm[j2 * 2 + 1] * d1 + Cc[j2];
      gh2 = bhh_g[j2];
    }
#pragma unroll 8
    for (int k = 0; k < 128; ++k) {
      float hv = h_lds[k];
      gh1 += whhT[k * 384 + j] * hv;        // coalesced over j
      if (lo) gh2 += whhT[k * 384 + j2] * hv;
    }
    float n_val = 0.f;
    if (lo) {
      float r = 1.f / (1.f + expf(-(gi1 + gh1)));
      n_val = tanhf(gi2 + r * gh2);         // n = tanh(i_n + r*h_n)
    } else {
      z_lds[t - 128] = 1.f / (1.f + expf(-(gi1 + gh1)));
    }
    __syncthreads();
    if (lo) {
      float z = z_lds[t];
      h_lds[t] = (1.f - z) * n_val + z * h_lds[t];
    }
    __syncthreads();

    // ---- u3 = W3 @ h_new  (split K across thread halves) ----
    {
      int hh = t & 127, half = t >> 7;
      const float* base = W3T + (half * 64) * 128 + hh;
      float p = 0.f;
#pragma unroll 8
      for (int k = 0; k < 64; ++k)
        p += base[k * 128] * h_lds[half * 64 + k];
      part[t] = p;
    }
    __syncthreads();
    if (lo) u3[t] = part[t] + part[t + 128];
    __syncthreads();

    // ---- attention scores a[s] = sum_h v[h] tanh(preA[h,s] + u3[h]) ----
    {
      int s = t & 63, q = t >> 6;
      float p = 0.f;
#pragma unroll 8
      for (int i = 0; i < 32; ++i) {
        int h = q * 32 + i;
        p += attn_v[h] * tanhf(preA[h * 65 + s] + u3[h]);
      }
      red[s * 4 + q] = p;
    }
    __syncthreads();
    if (t < 64) {  // wave 0: softmax over s
      float4 rr = *(const float4*)&red[t * 4];
      float a = rr.x + rr.y + rr.z + rr.w;
      float m = a;
      for (int off = 32; off; off >>= 1) m = fmaxf(m, __shfl_xor(m, off));
      float e = expf(a - m);
      float ssum = e;
      for (int off = 32; off; off >>= 1) ssum += __shfl_xor(ssum, off);
      attns[t] = e / ssum;
    }
    __syncthreads();

    // ---- u2 = (P2@static_h) @ attns   (Q is LDS-resident) ----
    {
      int hh = t & 127, half = t >> 7;
      float p = 0.f;
#pragma unroll 8
      for (int s2 = 0; s2 < 32; ++s2) {
        int s = half * 32 + s2;
        p += Qs[hh * 65 + s] * attns[s];
      }
      part[t] = p;
    }
    __syncthreads();
    if (lo) u2[t] = part[t] + part[t + 128];
    __syncthreads();

    // ---- pointer logits l[s] = sum_h pv[h] tanh(preP[h,s] + u2[h]) ----
    {
      int s = t & 63, q = t >> 6;
      float p = 0.f;
#pragma unroll 8
      for (int i = 0; i < 32; ++i) {
        int h = q * 32 + i;
        p += ptr_v[h] * tanhf(preP[h * 65 + s] + u2[h]);
      }
      red[s * 4 + q] = p;
    }
    __syncthreads();
    if (t < 64) {  // wave 0: argmax (first-index tiebreak) + log-softmax
      float4 rr = *(const float4*)&red[t * 4];
      float l = rr.x + rr.y + rr.z + rr.w;
      float v = l;
      int idx = t;
      for (int off = 32; off; off >>= 1) {
        float ov = __shfl_xor(v, off);
        int oi = __shfl_xor(idx, off);
        if (ov > v || (ov == v && oi < idx)) { v = ov; idx = oi; }
      }
      float e = expf(l - v);
      float ssum = e;
      for (int off = 32; off; off >>= 1) ssum += __shfl_xor(ssum, off);
      if (t == 0) {
        out[b * 64 + step] = (float)idx;             // tour_idx (as f32)
        out[8192 + b * 64 + step] = -logf(ssum);     // v - (v + log ssum)
        dec[0] = stt[idx];                           // next dec_in = static[:,ptr]
        dec[1] = stt[64 + idx];
      }
    }
    __syncthreads();
  }
}

extern "C" void kernel_launch(void* const* d_in, const int* in_sizes, int n_in,
                              void* d_out, int out_size, void* d_ws, size_t ws_size,
                              hipStream_t stream) {
  const float* statics  = (const float*)d_in[0];
  const float* dynamics = (const float*)d_in[1];
  const float* x0       = (const float*)d_in[2];
  const float* sw       = (const float*)d_in[3];
  const float* sb       = (const float*)d_in[4];
  const float* dw       = (const float*)d_in[5];
  const float* db       = (const float*)d_in[6];
  const float* decw     = (const float*)d_in[7];
  const float* decb     = (const float*)d_in[8];
  const float* wih      = (const float*)d_in[9];
  const float* whh      = (const float*)d_in[10];
  const float* bih      = (const float*)d_in[11];
  const float* bhh      = (const float*)d_in[12];
  const float* attn_v   = (const float*)d_in[13];
  const float* attn_W   = (const float*)d_in[14];
  const float* ptr_v    = (const float*)d_in[15];
  const float* ptr_W    = (const float*)d_in[16];
  float* ws  = (float*)d_ws;
  float* out = (float*)d_out;

  hipLaunchKernelGGL(prep_small, dim3(96), dim3(256), 0, stream,
                     whh, attn_W, wih, decw, decb, bih, ws);
  hipLaunchKernelGGL(prep_big, dim3(1024), dim3(256), 0, stream,
                     statics, dynamics, sw, sb, dw, db, attn_W, ptr_W, ws);
  hipLaunchKernelGGL(drl4tsp_main, dim3(128), dim3(256), 0, stream,
                     statics, x0, bhh, attn_v, ptr_v, ws, out);
}

// Round 2
// 440.351 us; speedup vs baseline: 3.9778x; 3.9778x over previous
//
#include <hip/hip_runtime.h>
#include <math.h>

// Problem dims (fixed by reference)
//   B=128, S=64, H=128, STATIC=DYNAMIC=2
// Outputs: tour_idx [B,S] (written as float), tour_logp [B,S]  -> d_out 16384 f32

// ---------------- ws layout (float offsets) ----------------
#define WS_WHH_T 0                       // [128][384]  whh_T[k][j] = whh[j][k]
#define WS_W3T   49152                   // [128][128]  W3T[k][h] = attn_W[h][256+k]
#define WS_M     65536                   // [384][2]    M = wih @ decoder_w
#define WS_C     66304                   // [384]       c = wih @ decoder_b + bih
#define WS_PREA  66688                   // [B][128][64] W1@static_h + W2@dynamic_h
#define WS_PREP  (WS_PREA + 128*8192)    // [B][128][64] P1@static_h
#define WS_Q     (WS_PREP + 128*8192)    // [B][128][64] P2@static_h

// ---------------- tiny precompute: transposes + GRU input-path folding ----
__global__ __launch_bounds__(256) void prep_small(
    const float* __restrict__ whh, const float* __restrict__ attn_W,
    const float* __restrict__ wih, const float* __restrict__ decw,
    const float* __restrict__ decb, const float* __restrict__ bih,
    float* __restrict__ ws) {
  int gid = blockIdx.x * 256 + threadIdx.x;
  int nth = gridDim.x * 256;
  float* whhT = ws + WS_WHH_T;
  float* W3T  = ws + WS_W3T;
  float* Mm   = ws + WS_M;
  float* Cc   = ws + WS_C;
  for (int idx = gid; idx < 384 * 128; idx += nth) {
    int k = idx / 384, j = idx % 384;        // out coalesced over j
    whhT[idx] = whh[j * 128 + k];
  }
  for (int idx = gid; idx < 128 * 128; idx += nth) {
    int k = idx / 128, h = idx % 128;
    W3T[idx] = attn_W[h * 384 + 256 + k];
  }
  if (gid < 384) {
    int j = gid;
    float m0 = 0.f, m1 = 0.f, cc = 0.f;
    for (int k = 0; k < 128; ++k) {
      float w = wih[j * 128 + k];
      m0 += w * decw[k * 2 + 0];
      m1 += w * decw[k * 2 + 1];
      cc += w * decb[k];
    }
    Mm[j * 2 + 0] = m0;
    Mm[j * 2 + 1] = m1;
    Cc[j] = cc + bih[j];
  }
}

// ---------------- big precompute: preA / preP / Q per batch --------------
// grid: 1024 blocks = (b, hq): b = bid>>3, hq = bid&7 owns 16 h-rows
__global__ __launch_bounds__(256) void prep_big(
    const float* __restrict__ statics, const float* __restrict__ dynamics,
    const float* __restrict__ sw, const float* __restrict__ sb,
    const float* __restrict__ dw, const float* __restrict__ db,
    const float* __restrict__ attn_W, const float* __restrict__ ptr_W,
    float* __restrict__ ws) {
  __shared__ __align__(16) float sh[128 * 64];
  __shared__ __align__(16) float dh[128 * 64];
  __shared__ float st[128];
  __shared__ float dy[128];
  int b = blockIdx.x >> 3;
  int hq = blockIdx.x & 7;
  int t = threadIdx.x;
  if (t < 128) st[t] = statics[b * 128 + t];
  else         dy[t - 128] = dynamics[b * 128 + (t - 128)];
  __syncthreads();
  for (int e = t; e < 8192; e += 256) {
    int h = e >> 6, s = e & 63;
    sh[e] = sw[h * 2 + 0] * st[s] + sw[h * 2 + 1] * st[64 + s] + sb[h];
    dh[e] = dw[h * 2 + 0] * dy[s] + dw[h * 2 + 1] * dy[64 + s] + db[h];
  }
  __syncthreads();
  int hh = hq * 16 + (t >> 4);
  int s0 = (t & 15) * 4;
  float4 pA = {0, 0, 0, 0}, pP = {0, 0, 0, 0}, qq = {0, 0, 0, 0};
  for (int k = 0; k < 128; ++k) {
    float4 sv = *(const float4*)&sh[k * 64 + s0];
    float4 dv = *(const float4*)&dh[k * 64 + s0];
    float w1 = attn_W[hh * 384 + k];
    float w2 = attn_W[hh * 384 + 128 + k];
    float p1 = ptr_W[hh * 256 + k];
    float p2 = ptr_W[hh * 256 + 128 + k];
    pA.x += w1 * sv.x + w2 * dv.x;  pA.y += w1 * sv.y + w2 * dv.y;
    pA.z += w1 * sv.z + w2 * dv.z;  pA.w += w1 * sv.w + w2 * dv.w;
    pP.x += p1 * sv.x;  pP.y += p1 * sv.y;  pP.z += p1 * sv.z;  pP.w += p1 * sv.w;
    qq.x += p2 * sv.x;  qq.y += p2 * sv.y;  qq.z += p2 * sv.z;  qq.w += p2 * sv.w;
  }
  int o = b * 8192 + hh * 64 + s0;
  *(float4*)&ws[WS_PREA + o] = pA;
  *(float4*)&ws[WS_PREP + o] = pP;
  *(float4*)&ws[WS_Q + o]    = qq;
}

// ---------------- main recurrence: 1 block per batch, 64 steps ----------
// 512 threads = 8 waves (2/SIMD).  All step-invariant weights live in
// REGISTERS (whh 96f, W3 32f, Q 16f, preA/preP 32f per thread); LDS holds
// only h, reduction scratch, and score buffers (~16 KB, conflict-free).
__global__ __launch_bounds__(512) void drl4tsp_main(
    const float* __restrict__ statics, const float* __restrict__ x0,
    const float* __restrict__ bhh_g, const float* __restrict__ attn_v,
    const float* __restrict__ ptr_v, const float* __restrict__ ws,
    float* __restrict__ out) {
  __shared__ float h_lds[128];
  __shared__ float z_lds[128];
  __shared__ float gpart[1536];   // [kq][384] GRU partials
  __shared__ float u3p[512];      // [kq][128]
  __shared__ float u2p[512];      // [kq][128]
  __shared__ float red[576];      // [64][9] padded score partials
  __shared__ float attns[64];
  __shared__ float avs[128];
  __shared__ float pvs[128];
  __shared__ float stt[128];
  __shared__ float dec[2];

  const int b  = blockIdx.x;
  const int t  = threadIdx.x;
  const int jj = t & 127;   // 0..127
  const int kq = t >> 7;    // 0..3  (k-quarter / s-quarter)
  const int ss = t & 63;    // 0..63
  const int sg = t >> 6;    // 0..7  (h-group of 16)

  const float* whhT = ws + WS_WHH_T;
  const float* W3T  = ws + WS_W3T;
  const float* Mm   = ws + WS_M;
  const float* Cc   = ws + WS_C;

  // ---- register-resident weights ----
  float wr0[32], wr1[32], wr2[32], w3r[32];
#pragma unroll
  for (int k = 0; k < 32; ++k) {
    int kk = kq * 32 + k;
    wr0[k] = whhT[kk * 384 + jj];          // whh row jj      (r gate)
    wr1[k] = whhT[kk * 384 + 128 + jj];    // whh row jj+128  (z gate)
    wr2[k] = whhT[kk * 384 + 256 + jj];    // whh row jj+256  (n gate)
    w3r[k] = W3T[kk * 128 + jj];
  }
  float qr[16], pa[16], pp[16];
#pragma unroll
  for (int i = 0; i < 16; ++i) {
    qr[i] = ws[WS_Q    + b * 8192 + jj * 64 + kq * 16 + i];
    pa[i] = ws[WS_PREA + b * 8192 + (sg * 16 + i) * 64 + ss];
    pp[i] = ws[WS_PREP + b * 8192 + (sg * 16 + i) * 64 + ss];
  }
  float mA0 = 0, mA1 = 0, cA = 0, bA = 0, mB0 = 0, mB1 = 0, cB = 0, bB = 0;
  if (t < 256) { mA0 = Mm[t * 2]; mA1 = Mm[t * 2 + 1]; cA = Cc[t]; bA = bhh_g[t]; }
  if (t < 128) {
    int r2 = t + 256;
    mB0 = Mm[r2 * 2]; mB1 = Mm[r2 * 2 + 1]; cB = Cc[r2]; bB = bhh_g[r2];
  }

  if (t < 128) {
    stt[t] = statics[b * 128 + t];
    h_lds[t] = 0.f;
    avs[t] = attn_v[t];
    pvs[t] = ptr_v[t];
  }
  if (t < 2) dec[t] = x0[t];
  __syncthreads();

  for (int step = 0; step < 64; ++step) {
    float d0 = dec[0], d1 = dec[1];
    // ---- P1: GRU hidden-path partials (register weights, LDS-broadcast h)
    {
      float p0 = 0.f, p1 = 0.f, p2 = 0.f;
#pragma unroll
      for (int k = 0; k < 32; ++k) {
        float hv = h_lds[kq * 32 + k];
        p0 += wr0[k] * hv;
        p1 += wr1[k] * hv;
        p2 += wr2[k] * hv;
      }
      gpart[kq * 384 + jj]       = p0;
      gpart[kq * 384 + 128 + jj] = p1;
      gpart[kq * 384 + 256 + jj] = p2;
    }
    __syncthreads();                                     // B1
    // ---- P2: gates. t<128: r + n; t in [128,256): z
    float nv = 0.f;
    if (t < 256) {
      float gh = bA + gpart[t] + gpart[384 + t] + gpart[768 + t] + gpart[1152 + t];
      float gi = mA0 * d0 + mA1 * d1 + cA;
      if (t < 128) {
        float r = 1.f / (1.f + expf(-(gi + gh)));
        int r2 = t + 256;
        float ghn = bB + gpart[r2] + gpart[384 + r2] + gpart[768 + r2] + gpart[1152 + r2];
        float gin = mB0 * d0 + mB1 * d1 + cB;
        nv = tanhf(gin + r * ghn);
      } else {
        z_lds[t - 128] = 1.f / (1.f + expf(-(gi + gh)));
      }
    }
    __syncthreads();                                     // B2
    if (t < 128) {
      float z = z_lds[t];
      h_lds[t] = (1.f - z) * nv + z * h_lds[t];
    }
    __syncthreads();                                     // B3
    // ---- P4: u3 = W3 @ h_new partials
    {
      float p = 0.f;
#pragma unroll
      for (int k = 0; k < 32; ++k) p += w3r[k] * h_lds[kq * 32 + k];
      u3p[kq * 128 + jj] = p;
    }
    __syncthreads();                                     // B4
    // ---- P5: attention scores a[s] = sum_h av[h] tanh(preA[h,s]+u3[h])
    {
      float acc = 0.f;
#pragma unroll
      for (int i = 0; i < 16; ++i) {
        int h = sg * 16 + i;
        float u3h = u3p[h] + u3p[128 + h] + u3p[256 + h] + u3p[384 + h];
        acc += avs[h] * tanhf(pa[i] + u3h);
      }
      red[ss * 9 + sg] = acc;
    }
    __syncthreads();                                     // B5
    // ---- P6: softmax over s (wave 0)
    if (t < 64) {
      const float* r9 = &red[t * 9];
      float a = r9[0] + r9[1] + r9[2] + r9[3] + r9[4] + r9[5] + r9[6] + r9[7];
      float m = a;
      for (int off = 32; off; off >>= 1) m = fmaxf(m, __shfl_xor(m, off));
      float e = expf(a - m);
      float ssum = e;
      for (int off = 32; off; off >>= 1) ssum += __shfl_xor(ssum, off);
      attns[t] = e / ssum;
    }
    __syncthreads();                                     // B6
    // ---- P7: u2 = Q @ attns partials (register Q)
    {
      float p = 0.f;
#pragma unroll
      for (int i = 0; i < 16; ++i) p += qr[i] * attns[kq * 16 + i];
      u2p[kq * 128 + jj] = p;
    }
    __syncthreads();                                     // B7
    // ---- P8: pointer logits l[s] = sum_h pv[h] tanh(preP[h,s]+u2[h])
    {
      float acc = 0.f;
#pragma unroll
      for (int i = 0; i < 16; ++i) {
        int h = sg * 16 + i;
        float u2h = u2p[h] + u2p[128 + h] + u2p[256 + h] + u2p[384 + h];
        acc += pvs[h] * tanhf(pp[i] + u2h);
      }
      red[ss * 9 + sg] = acc;
    }
    __syncthreads();                                     // B8
    // ---- P9: argmax (first-index tiebreak) + log-softmax + feedback
    if (t < 64) {
      const float* r9 = &red[t * 9];
      float l = r9[0] + r9[1] + r9[2] + r9[3] + r9[4] + r9[5] + r9[6] + r9[7];
      float v = l;
      int idx = t;
      for (int off = 32; off; off >>= 1) {
        float ov = __shfl_xor(v, off);
        int oi = __shfl_xor(idx, off);
        if (ov > v || (ov == v && oi < idx)) { v = ov; idx = oi; }
      }
      float e = expf(l - v);
      float ssum = e;
      for (int off = 32; off; off >>= 1) ssum += __shfl_xor(ssum, off);
      if (t == 0) {
        out[b * 64 + step] = (float)idx;             // tour_idx (as f32)
        out[8192 + b * 64 + step] = -logf(ssum);     // logp of the argmax
        dec[0] = stt[idx];                           // next dec_in
        dec[1] = stt[64 + idx];
      }
    }
    __syncthreads();                                     // B9
  }
}

extern "C" void kernel_launch(void* const* d_in, const int* in_sizes, int n_in,
                              void* d_out, int out_size, void* d_ws, size_t ws_size,
                              hipStream_t stream) {
  const float* statics  = (const float*)d_in[0];
  const float* dynamics = (const float*)d_in[1];
  const float* x0       = (const float*)d_in[2];
  const float* sw       = (const float*)d_in[3];
  const float* sb       = (const float*)d_in[4];
  const float* dw       = (const float*)d_in[5];
  const float* db       = (const float*)d_in[6];
  const float* decw     = (const float*)d_in[7];
  const float* decb     = (const float*)d_in[8];
  const float* wih      = (const float*)d_in[9];
  const float* whh      = (const float*)d_in[10];
  const float* bih      = (const float*)d_in[11];
  const float* bhh      = (const float*)d_in[12];
  const float* attn_v   = (const float*)d_in[13];
  const float* attn_W   = (const float*)d_in[14];
  const float* ptr_v    = (const float*)d_in[15];
  const float* ptr_W    = (const float*)d_in[16];
  float* ws  = (float*)d_ws;
  float* out = (float*)d_out;

  hipLaunchKernelGGL(prep_small, dim3(96), dim3(256), 0, stream,
                     whh, attn_W, wih, decw, decb, bih, ws);
  hipLaunchKernelGGL(prep_big, dim3(1024), dim3(256), 0, stream,
                     statics, dynamics, sw, sb, dw, db, attn_W, ptr_W, ws);
  hipLaunchKernelGGL(drl4tsp_main, dim3(128), dim3(512), 0, stream,
                     statics, x0, bhh, attn_v, ptr_v, ws, out);
}

// Round 3
// 334.074 us; speedup vs baseline: 5.2433x; 1.3181x over previous
//
#include <hip/hip_runtime.h>
#include <math.h>

// Problem dims (fixed by reference)
//   B=128, S=64, H=128, STATIC=DYNAMIC=2
// Outputs: tour_idx [B,S] (as f32), tour_logp [B,S]  -> d_out 16384 f32

// ---------------- ws layout (float offsets) ----------------
#define WS_M     0                       // [384][2]   M = wih @ decoder_w
#define WS_C     768                     // [384]      c = wih @ decoder_b + bih
#define WS_PREA  1152                    // [B][128][64] W1@static_h + W2@dynamic_h
#define WS_PREP  (WS_PREA + 128*8192)    // [B][128][64] P1@static_h
#define WS_Q     (WS_PREP + 128*8192)    // [B][128][64] P2@static_h

// swizzled LDS index for 128-entry vectors read at stride 16 (kills bank aliasing)
#define SW(h) ((h) + ((h) >> 3))

__device__ __forceinline__ float fast_tanh(float x) {
  float e = __expf(2.0f * x);
  return 1.0f - 2.0f * __builtin_amdgcn_rcpf(e + 1.0f);
}

// ---------------- tiny precompute: GRU input-path folding ----------------
__global__ __launch_bounds__(256) void prep_small(
    const float* __restrict__ wih, const float* __restrict__ decw,
    const float* __restrict__ decb, const float* __restrict__ bih,
    float* __restrict__ ws) {
  int gid = blockIdx.x * 256 + threadIdx.x;
  if (gid < 384) {
    float m0 = 0.f, m1 = 0.f, cc = 0.f;
    for (int k = 0; k < 128; ++k) {
      float w = wih[gid * 128 + k];
      m0 += w * decw[k * 2 + 0];
      m1 += w * decw[k * 2 + 1];
      cc += w * decb[k];
    }
    ws[WS_M + gid * 2 + 0] = m0;
    ws[WS_M + gid * 2 + 1] = m1;
    ws[WS_C + gid] = cc + bih[gid];
  }
}

// ---------------- big precompute: preA / preP / Q per batch --------------
__global__ __launch_bounds__(256) void prep_big(
    const float* __restrict__ statics, const float* __restrict__ dynamics,
    const float* __restrict__ sw, const float* __restrict__ sb,
    const float* __restrict__ dw, const float* __restrict__ db,
    const float* __restrict__ attn_W, const float* __restrict__ ptr_W,
    float* __restrict__ ws) {
  __shared__ __align__(16) float sh[128 * 64];
  __shared__ __align__(16) float dh[128 * 64];
  __shared__ float st[128];
  __shared__ float dy[128];
  int b = blockIdx.x >> 3;
  int hq = blockIdx.x & 7;
  int t = threadIdx.x;
  if (t < 128) st[t] = statics[b * 128 + t];
  else         dy[t - 128] = dynamics[b * 128 + (t - 128)];
  __syncthreads();
  for (int e = t; e < 8192; e += 256) {
    int h = e >> 6, s = e & 63;
    sh[e] = sw[h * 2 + 0] * st[s] + sw[h * 2 + 1] * st[64 + s] + sb[h];
    dh[e] = dw[h * 2 + 0] * dy[s] + dw[h * 2 + 1] * dy[64 + s] + db[h];
  }
  __syncthreads();
  int hh = hq * 16 + (t >> 4);
  int s0 = (t & 15) * 4;
  float4 pA = {0, 0, 0, 0}, pP = {0, 0, 0, 0}, qq = {0, 0, 0, 0};
  for (int k = 0; k < 128; ++k) {
    float4 sv = *(const float4*)&sh[k * 64 + s0];
    float4 dv = *(const float4*)&dh[k * 64 + s0];
    float w1 = attn_W[hh * 384 + k];
    float w2 = attn_W[hh * 384 + 128 + k];
    float p1 = ptr_W[hh * 256 + k];
    float p2 = ptr_W[hh * 256 + 128 + k];
    pA.x += w1 * sv.x + w2 * dv.x;  pA.y += w1 * sv.y + w2 * dv.y;
    pA.z += w1 * sv.z + w2 * dv.z;  pA.w += w1 * sv.w + w2 * dv.w;
    pP.x += p1 * sv.x;  pP.y += p1 * sv.y;  pP.z += p1 * sv.z;  pP.w += p1 * sv.w;
    qq.x += p2 * sv.x;  qq.y += p2 * sv.y;  qq.z += p2 * sv.z;  qq.w += p2 * sv.w;
  }
  int o = b * 8192 + hh * 64 + s0;
  *(float4*)&ws[WS_PREA + o] = pA;
  *(float4*)&ws[WS_PREP + o] = pP;
  *(float4*)&ws[WS_Q + o]    = qq;
}

// ---------------- main recurrence: 1 block per batch, 64 steps ----------
// 512 threads = 8 waves.  All cross-thread reductions are intra-wave
// shuffles; 5 barriers/step; GRU matvec pipelined into the u3 pass (gh sums
// carried in registers across steps); fast tanh on the 16K hot tanh/step.
__global__ __launch_bounds__(512, 2) void drl4tsp_main(
    const float* __restrict__ statics, const float* __restrict__ x0,
    const float* __restrict__ whh, const float* __restrict__ attn_W,
    const float* __restrict__ bhh_g, const float* __restrict__ attn_v,
    const float* __restrict__ ptr_v, const float* __restrict__ ws,
    float* __restrict__ out) {
  __shared__ __align__(16) float h_lds[128];
  __shared__ float u3_lds[144];
  __shared__ float u2_lds[144];
  __shared__ float avs[144];
  __shared__ float pvs[144];
  __shared__ float a_lds[64];
  __shared__ float l_lds[64];
  __shared__ float stt[128];

  const int b    = blockIdx.x;
  const int t    = threadIdx.x;
  const int lane = t & 63;
  const int g    = t >> 2;   // 0..127 : row (M1 mapping, 4-lane groups)
  const int q    = t & 3;    // k/s quarter within group
  const int s2   = t >> 3;   // 0..63  : s column (M2 mapping, 8-lane groups)
  const int hg   = t & 7;    // h-group of 16

  // ---- one-time register-resident weights ----
  float wr0[32], wr1[32], wr2[32], w3r[32];
  {
    const float4* pr = (const float4*)(whh + g * 128 + q * 32);
    const float4* pz = (const float4*)(whh + (128 + g) * 128 + q * 32);
    const float4* pn = (const float4*)(whh + (256 + g) * 128 + q * 32);
    const float4* p3 = (const float4*)(attn_W + g * 384 + 256 + q * 32);
#pragma unroll
    for (int i = 0; i < 8; ++i) {
      float4 a = pr[i], c = pz[i], d = pn[i], e = p3[i];
      wr0[4*i] = a.x; wr0[4*i+1] = a.y; wr0[4*i+2] = a.z; wr0[4*i+3] = a.w;
      wr1[4*i] = c.x; wr1[4*i+1] = c.y; wr1[4*i+2] = c.z; wr1[4*i+3] = c.w;
      wr2[4*i] = d.x; wr2[4*i+1] = d.y; wr2[4*i+2] = d.z; wr2[4*i+3] = d.w;
      w3r[4*i] = e.x; w3r[4*i+1] = e.y; w3r[4*i+2] = e.z; w3r[4*i+3] = e.w;
    }
  }
  float qr[16], pa[16], pp[16];
  {
    const float4* pq = (const float4*)(ws + WS_Q + b * 8192 + g * 64 + q * 16);
#pragma unroll
    for (int i = 0; i < 4; ++i) {
      float4 v = pq[i];
      qr[4*i] = v.x; qr[4*i+1] = v.y; qr[4*i+2] = v.z; qr[4*i+3] = v.w;
    }
#pragma unroll
    for (int i = 0; i < 16; ++i) {
      int h = hg * 16 + i;
      pa[i] = ws[WS_PREA + b * 8192 + h * 64 + s2];
      pp[i] = ws[WS_PREP + b * 8192 + h * 64 + s2];
    }
  }
  const float* Mm = ws + WS_M;
  const float* Cc = ws + WS_C;
  const float mR0 = Mm[g * 2],         mR1 = Mm[g * 2 + 1];
  const float cR  = Cc[g],             bR  = bhh_g[g];
  const float mZ0 = Mm[(128+g) * 2],   mZ1 = Mm[(128+g) * 2 + 1];
  const float cZ  = Cc[128 + g],       bZ  = bhh_g[128 + g];
  const float mN0 = Mm[(256+g) * 2],   mN1 = Mm[(256+g) * 2 + 1];
  const float cN  = Cc[256 + g],       bN  = bhh_g[256 + g];

  if (t < 128) {
    stt[t] = statics[b * 128 + t];
    avs[SW(t)] = attn_v[t];
    pvs[SW(t)] = ptr_v[t];
  }
  __syncthreads();

  float hreg = 0.f, ghr = 0.f, ghz = 0.f, ghn = 0.f;  // gh = whh@h (h0=0)
  float d0 = x0[0], d1 = x0[1];

  for (int step = 0; step < 64; ++step) {
    // ---- P1: gates (pointwise; gh sums carried from prev step's P2) ----
    {
      float r = 1.f / (1.f + expf(-(mR0 * d0 + mR1 * d1 + cR + ghr + bR)));
      float z = 1.f / (1.f + expf(-(mZ0 * d0 + mZ1 * d1 + cZ + ghz + bZ)));
      float n = tanhf(mN0 * d0 + mN1 * d1 + cN + r * (ghn + bN));
      hreg = (1.f - z) * n + z * hreg;
      if (q == 0) h_lds[g] = hreg;
    }
    __syncthreads();                                   // A
    // ---- P2: u3 = W3@h_new  +  next-step gh = whh@h_new (shared reads) --
    {
      float u3p = 0.f;
      ghr = 0.f; ghz = 0.f; ghn = 0.f;
#pragma unroll
      for (int k4 = 0; k4 < 8; ++k4) {
        float4 hv = *(const float4*)&h_lds[q * 32 + k4 * 4];
        int k = k4 * 4;
        u3p += w3r[k]*hv.x + w3r[k+1]*hv.y + w3r[k+2]*hv.z + w3r[k+3]*hv.w;
        ghr += wr0[k]*hv.x + wr0[k+1]*hv.y + wr0[k+2]*hv.z + wr0[k+3]*hv.w;
        ghz += wr1[k]*hv.x + wr1[k+1]*hv.y + wr1[k+2]*hv.z + wr1[k+3]*hv.w;
        ghn += wr2[k]*hv.x + wr2[k+1]*hv.y + wr2[k+2]*hv.z + wr2[k+3]*hv.w;
      }
      u3p += __shfl_xor(u3p, 1); u3p += __shfl_xor(u3p, 2);
      ghr += __shfl_xor(ghr, 1); ghr += __shfl_xor(ghr, 2);
      ghz += __shfl_xor(ghz, 1); ghz += __shfl_xor(ghz, 2);
      ghn += __shfl_xor(ghn, 1); ghn += __shfl_xor(ghn, 2);
      if (q == 0) u3_lds[SW(g)] = u3p;
    }
    __syncthreads();                                   // B
    // ---- P3: attn scores a[s] = sum_h av[h] tanh(preA[h,s]+u3[h]) ------
    {
      float acc = 0.f;
#pragma unroll
      for (int i = 0; i < 16; ++i) {
        int h = hg * 16 + i;
        acc += avs[SW(h)] * fast_tanh(pa[i] + u3_lds[SW(h)]);
      }
      acc += __shfl_xor(acc, 1); acc += __shfl_xor(acc, 2); acc += __shfl_xor(acc, 4);
      if (hg == 0) a_lds[s2] = acc;
    }
    __syncthreads();                                   // C
    // ---- P4: softmax (wave-redundant) + u2 = Q@attns -------------------
    {
      float a = a_lds[lane];
      float m = a;
      for (int off = 32; off; off >>= 1) m = fmaxf(m, __shfl_xor(m, off));
      float e = expf(a - m);
      float sum = e;
      for (int off = 32; off; off >>= 1) sum += __shfl_xor(sum, off);
      float rsum = 1.f / sum;
      float p = 0.f;
#pragma unroll
      for (int i = 0; i < 16; ++i) p += qr[i] * __shfl(e, q * 16 + i);
      p *= rsum;
      p += __shfl_xor(p, 1); p += __shfl_xor(p, 2);
      if (q == 0) u2_lds[SW(g)] = p;
    }
    __syncthreads();                                   // D
    // ---- P5: ptr logits l[s] = sum_h pv[h] tanh(preP[h,s]+u2[h]) -------
    {
      float acc = 0.f;
#pragma unroll
      for (int i = 0; i < 16; ++i) {
        int h = hg * 16 + i;
        acc += pvs[SW(h)] * fast_tanh(pp[i] + u2_lds[SW(h)]);
      }
      acc += __shfl_xor(acc, 1); acc += __shfl_xor(acc, 2); acc += __shfl_xor(acc, 4);
      if (hg == 0) l_lds[s2] = acc;
    }
    __syncthreads();                                   // E
    // ---- P6: argmax + logp + dec feedback (wave-redundant, no barrier) -
    {
      float L = l_lds[lane];
      float v = L;
      int idx = lane;
      for (int off = 32; off; off >>= 1) {
        float ov = __shfl_xor(v, off);
        int oi = __shfl_xor(idx, off);
        if (ov > v || (ov == v && oi < idx)) { v = ov; idx = oi; }
      }
      float e2 = expf(L - v);
      float s3 = e2;
      for (int off = 32; off; off >>= 1) s3 += __shfl_xor(s3, off);
      if (t == 0) {
        out[b * 64 + step] = (float)idx;           // tour_idx (as f32)
        out[8192 + b * 64 + step] = -logf(s3);     // logp of argmax
      }
      d0 = stt[idx];                               // broadcast LDS reads
      d1 = stt[64 + idx];
    }
    // no barrier: every buffer's next write is >=2 barriers downstream
  }
}

extern "C" void kernel_launch(void* const* d_in, const int* in_sizes, int n_in,
                              void* d_out, int out_size, void* d_ws, size_t ws_size,
                              hipStream_t stream) {
  const float* statics  = (const float*)d_in[0];
  const float* dynamics = (const float*)d_in[1];
  const float* x0       = (const float*)d_in[2];
  const float* sw       = (const float*)d_in[3];
  const float* sb       = (const float*)d_in[4];
  const float* dw       = (const float*)d_in[5];
  const float* db       = (const float*)d_in[6];
  const float* decw     = (const float*)d_in[7];
  const float* decb     = (const float*)d_in[8];
  const float* wih      = (const float*)d_in[9];
  const float* whh      = (const float*)d_in[10];
  const float* bih      = (const float*)d_in[11];
  const float* bhh      = (const float*)d_in[12];
  const float* attn_v   = (const float*)d_in[13];
  const float* attn_W   = (const float*)d_in[14];
  const float* ptr_v    = (const float*)d_in[15];
  const float* ptr_W    = (const float*)d_in[16];
  float* ws  = (float*)d_ws;
  float* out = (float*)d_out;

  hipLaunchKernelGGL(prep_small, dim3(2), dim3(256), 0, stream,
                     wih, decw, decb, bih, ws);
  hipLaunchKernelGGL(prep_big, dim3(1024), dim3(256), 0, stream,
                     statics, dynamics, sw, sb, dw, db, attn_W, ptr_W, ws);
  hipLaunchKernelGGL(drl4tsp_main, dim3(128), dim3(512), 0, stream,
                     statics, x0, whh, attn_W, bhh, attn_v, ptr_v, ws, out);
}